// Round 1
// baseline (505.431 us; speedup 1.0000x reference)
//
#include <hip/hip_runtime.h>

typedef unsigned short u16;
typedef __attribute__((ext_vector_type(8))) short short8;
typedef __attribute__((ext_vector_type(4))) float f32x4;
typedef __attribute__((ext_vector_type(8))) float f32x8;

#define MFMA(a, b, c) __builtin_amdgcn_mfma_f32_16x16x32_bf16((a), (b), (c), 0, 0, 0)

__device__ __forceinline__ u16 f2bf(float f) {
    union { float f; unsigned int u; } v; v.f = f;
    unsigned int u = v.u;
    return (u16)((u + 0x7fffu + ((u >> 16) & 1u)) >> 16);
}

// ---------------- Kernel 1: QKV projection ----------------
// C[m,d] = sum_k X[m,k] * Wqkv[d,k];  scatter to Q/K/V bf16 [b,h,n,64], Q scaled.
__global__ __launch_bounds__(256) void qkv_gemm(const float* __restrict__ X,
                                                const float* __restrict__ W,
                                                u16* __restrict__ Qb,
                                                u16* __restrict__ Kb,
                                                u16* __restrict__ Vb) {
    const int m0 = blockIdx.x * 128;
    const int n0 = blockIdx.y * 128;
    const int tid = threadIdx.x;
    const int lane = tid & 63;
    const int w = tid >> 6;
    const int wm = (w >> 1) * 64, wn = (w & 1) * 64;
    const int lrow = lane & 15, rgrp = lane >> 4, lk = rgrp * 8;

    f32x4 acc[4][4] = {};
    const float* Xb = X + (size_t)(m0 + wm + lrow) * 768;
    const float* Wb = W + (size_t)(n0 + wn + lrow) * 768;

    for (int k0 = 0; k0 < 768; k0 += 32) {
        short8 a[4], b[4];
#pragma unroll
        for (int mf = 0; mf < 4; ++mf) {
            f32x8 xv = *(const f32x8*)(Xb + (size_t)mf * 16 * 768 + k0 + lk);
#pragma unroll
            for (int j = 0; j < 8; ++j) a[mf][j] = (short)f2bf(xv[j]);
        }
#pragma unroll
        for (int nf = 0; nf < 4; ++nf) {
            f32x8 wv = *(const f32x8*)(Wb + (size_t)nf * 16 * 768 + k0 + lk);
#pragma unroll
            for (int j = 0; j < 8; ++j) b[nf][j] = (short)f2bf(wv[j]);
        }
#pragma unroll
        for (int mf = 0; mf < 4; ++mf)
#pragma unroll
            for (int nf = 0; nf < 4; ++nf)
                acc[mf][nf] = MFMA(a[mf], b[nf], acc[mf][nf]);
    }

    const int which = n0 / 768;            // 0=q 1=k 2=v (tiles never straddle)
    u16* dst = (which == 0) ? Qb : (which == 1 ? Kb : Vb);
    const float scl = (which == 0) ? 0.125f : 1.0f;
#pragma unroll
    for (int mf = 0; mf < 4; ++mf)
#pragma unroll
        for (int nf = 0; nf < 4; ++nf)
#pragma unroll
            for (int r = 0; r < 4; ++r) {
                int m = m0 + wm + mf * 16 + rgrp * 4 + r;
                int d = n0 + wn + nf * 16 + lrow - which * 768;
                int h = d >> 6, e = d & 63;
                int bb = m >> 11, nseq = m & 2047;
                dst[(((size_t)bb * 12 + h) * 2048 + nseq) * 64 + e] = f2bf(acc[mf][nf][r] * scl);
            }
}

// ---------------- Kernel 2: flash attention ----------------
// One block = 128 q-rows of one (b,h). 4 waves x 32 rows. KBLK=64.
__global__ __launch_bounds__(256) void attn_kernel(const u16* __restrict__ Qb,
                                                   const u16* __restrict__ Kb,
                                                   const u16* __restrict__ Vb,
                                                   u16* __restrict__ AO) {
    __shared__ __align__(16) u16 vt[64 * 72];        // V^T : [d=64][k=64], pad 72
    __shared__ __align__(16) u16 pbuf[4 * 32 * 72];  // per-wave P: [32][64], pad 72

    const int bh = blockIdx.y;
    const int q0 = blockIdx.x * 128;
    const int tid = threadIdx.x;
    const int lane = tid & 63;
    const int w = tid >> 6;
    const int lrow = lane & 15, rgrp = lane >> 4, lk = rgrp * 8;

    const u16* Qp = Qb + (size_t)bh * 2048 * 64;
    const u16* Kp = Kb + (size_t)bh * 2048 * 64;
    const u16* Vp = Vb + (size_t)bh * 2048 * 64;

    // Q fragments stay in registers for the whole kernel (already scaled by 1/8)
    short8 qf[2][2];
#pragma unroll
    for (int mf = 0; mf < 2; ++mf)
#pragma unroll
        for (int ks = 0; ks < 2; ++ks)
            qf[mf][ks] = *(const short8*)(Qp + (size_t)(q0 + w * 32 + mf * 16 + lrow) * 64 + ks * 32 + lk);

    f32x4 oacc[2][4] = {};
    float mrun[2][4], lrun[2][4];
#pragma unroll
    for (int mf = 0; mf < 2; ++mf)
#pragma unroll
        for (int r = 0; r < 4; ++r) { mrun[mf][r] = -1e30f; lrun[mf][r] = 0.f; }

    u16* Pw = pbuf + w * 32 * 72;

    for (int kt = 0; kt < 32; ++kt) {
        __syncthreads();  // protect vt against overwrite while previous PV reads finish
        // stage V^T into LDS
#pragma unroll
        for (int pass = 0; pass < 2; ++pass) {
            int idx = tid + pass * 256;
            int r = idx >> 3;
            int c0 = (idx & 7) * 8;
            short8 vv = *(const short8*)(Vp + (size_t)(kt * 64 + r) * 64 + c0);
#pragma unroll
            for (int i = 0; i < 8; ++i) vt[(c0 + i) * 72 + r] = (u16)vv[i];
        }
        __syncthreads();

        // S = Q K^T  (K fragments direct from global: row-contiguous)
        f32x4 sacc[2][4] = {};
#pragma unroll
        for (int nf = 0; nf < 4; ++nf)
#pragma unroll
            for (int ks = 0; ks < 2; ++ks) {
                short8 kf = *(const short8*)(Kp + (size_t)(kt * 64 + nf * 16 + lrow) * 64 + ks * 32 + lk);
                sacc[0][nf] = MFMA(qf[0][ks], kf, sacc[0][nf]);
                sacc[1][nf] = MFMA(qf[1][ks], kf, sacc[1][nf]);
            }

        // online softmax (rows live on 16-lane groups; reduce over l&15)
#pragma unroll
        for (int mf = 0; mf < 2; ++mf)
#pragma unroll
            for (int r = 0; r < 4; ++r) {
                float mx = fmaxf(fmaxf(sacc[mf][0][r], sacc[mf][1][r]),
                                 fmaxf(sacc[mf][2][r], sacc[mf][3][r]));
#pragma unroll
                for (int off = 1; off < 16; off <<= 1) mx = fmaxf(mx, __shfl_xor(mx, off));
                float mnew = fmaxf(mrun[mf][r], mx);
                float alpha = __expf(mrun[mf][r] - mnew);
                float rs = 0.f;
#pragma unroll
                for (int nf = 0; nf < 4; ++nf) {
                    float p = __expf(sacc[mf][nf][r] - mnew);
                    sacc[mf][nf][r] = p;
                    rs += p;
                }
#pragma unroll
                for (int off = 1; off < 16; off <<= 1) rs += __shfl_xor(rs, off);
                lrun[mf][r] = lrun[mf][r] * alpha + rs;
                mrun[mf][r] = mnew;
#pragma unroll
                for (int df = 0; df < 4; ++df) oacc[mf][df][r] *= alpha;
            }

        // P -> LDS (bf16), per-wave private region
#pragma unroll
        for (int mf = 0; mf < 2; ++mf)
#pragma unroll
            for (int nf = 0; nf < 4; ++nf)
#pragma unroll
                for (int r = 0; r < 4; ++r)
                    Pw[(mf * 16 + rgrp * 4 + r) * 72 + nf * 16 + lrow] = f2bf(sacc[mf][nf][r]);
        __syncthreads();

        // O += P V
#pragma unroll
        for (int ks = 0; ks < 2; ++ks) {
            short8 pa0 = *(const short8*)&Pw[(0 * 16 + lrow) * 72 + ks * 32 + lk];
            short8 pa1 = *(const short8*)&Pw[(1 * 16 + lrow) * 72 + ks * 32 + lk];
#pragma unroll
            for (int df = 0; df < 4; ++df) {
                short8 vf = *(const short8*)&vt[(df * 16 + lrow) * 72 + ks * 32 + lk];
                oacc[0][df] = MFMA(pa0, vf, oacc[0][df]);
                oacc[1][df] = MFMA(pa1, vf, oacc[1][df]);
            }
        }
    }

    // epilogue: normalize and write attn_out [b, n, h*64+d] bf16
    const int b = bh / 12, h = bh % 12;
#pragma unroll
    for (int mf = 0; mf < 2; ++mf)
#pragma unroll
        for (int r = 0; r < 4; ++r) {
            int row = q0 + w * 32 + mf * 16 + rgrp * 4 + r;
            float inv = 1.f / lrun[mf][r];
#pragma unroll
            for (int df = 0; df < 4; ++df)
                AO[((size_t)b * 2048 + row) * 768 + h * 64 + df * 16 + lrow] =
                    f2bf(oacc[mf][df][r] * inv);
        }
}

// ---------------- Kernel 3: output projection ----------------
// out[m,d] = sum_k AO[m,k] * Wp[d,k] + bias[d]  (fp32 out)
__global__ __launch_bounds__(256) void proj_gemm(const u16* __restrict__ A,
                                                 const float* __restrict__ W,
                                                 const float* __restrict__ bias,
                                                 float* __restrict__ out) {
    const int m0 = blockIdx.x * 128;
    const int n0 = blockIdx.y * 128;
    const int tid = threadIdx.x;
    const int lane = tid & 63;
    const int w = tid >> 6;
    const int wm = (w >> 1) * 64, wn = (w & 1) * 64;
    const int lrow = lane & 15, rgrp = lane >> 4, lk = rgrp * 8;

    f32x4 acc[4][4] = {};
    const u16* Ab = A + (size_t)(m0 + wm + lrow) * 768;
    const float* Wb = W + (size_t)(n0 + wn + lrow) * 768;

    for (int k0 = 0; k0 < 768; k0 += 32) {
        short8 a[4], b[4];
#pragma unroll
        for (int mf = 0; mf < 4; ++mf)
            a[mf] = *(const short8*)(Ab + (size_t)mf * 16 * 768 + k0 + lk);
#pragma unroll
        for (int nf = 0; nf < 4; ++nf) {
            f32x8 wv = *(const f32x8*)(Wb + (size_t)nf * 16 * 768 + k0 + lk);
#pragma unroll
            for (int j = 0; j < 8; ++j) b[nf][j] = (short)f2bf(wv[j]);
        }
#pragma unroll
        for (int mf = 0; mf < 4; ++mf)
#pragma unroll
            for (int nf = 0; nf < 4; ++nf)
                acc[mf][nf] = MFMA(a[mf], b[nf], acc[mf][nf]);
    }

#pragma unroll
    for (int nf = 0; nf < 4; ++nf) {
        int d = n0 + wn + nf * 16 + lrow;
        float bv = bias[d];
#pragma unroll
        for (int mf = 0; mf < 4; ++mf)
#pragma unroll
            for (int r = 0; r < 4; ++r) {
                int m = m0 + wm + mf * 16 + rgrp * 4 + r;
                out[(size_t)m * 768 + d] = acc[mf][nf][r] + bv;
            }
    }
}

extern "C" void kernel_launch(void* const* d_in, const int* in_sizes, int n_in,
                              void* d_out, int out_size, void* d_ws, size_t ws_size,
                              hipStream_t stream) {
    const float* x      = (const float*)d_in[0];
    const float* w_qkv  = (const float*)d_in[1];
    const float* w_proj = (const float*)d_in[2];
    const float* b_proj = (const float*)d_in[3];
    float* out = (float*)d_out;

    const size_t per = (size_t)48 * 2048 * 64;  // 6.29M elems per buffer
    u16* Qb = (u16*)d_ws;
    u16* Kb = Qb + per;
    u16* Vb = Kb + per;
    u16* AO = Vb + per;

    qkv_gemm<<<dim3(64, 18), 256, 0, stream>>>(x, w_qkv, Qb, Kb, Vb);
    attn_kernel<<<dim3(16, 48), 256, 0, stream>>>(Qb, Kb, Vb, AO);
    proj_gemm<<<dim3(64, 6), 256, 0, stream>>>(AO, w_proj, b_proj, out);
}